// Round 15
// baseline (138.543 us; speedup 1.0000x reference)
//
#include <hip/hip_runtime.h>
#include <math.h>

#define H 512
#define W 512
#define HW (H*W)
#define NB 4
#define NC 32

// ---- fused: [8 channels/group] score-conv partial + avgpool3x3 -> conv5x5 -> even max ----
// T14 software pipeline: while channel ci computes (phase2/phase3), channel ci+1's halo
// tile is already in flight into registers; ds_write happens next iteration. phase3(ci-1)
// is hoisted before the A-ready barrier so it overlaps staging writes.
__global__ __launch_bounds__(256) void k_whmax_sc(const float* __restrict__ color,
                                                  const float* __restrict__ wbbx,
                                                  const float* __restrict__ wscore,
                                                  float* __restrict__ pw,
                                                  float* __restrict__ scE) {
    __shared__ float A[38][140];   // rows Y0-3..Y0+34, cols X0-4..X0+135
    __shared__ float P[36][136];   // rows Y0-2..Y0+33, cols X0-2..X0+133

    const int t  = threadIdx.x;
    const int X0 = blockIdx.x * 128;
    const int Y0 = blockIdx.y * 32;
    const int b  = blockIdx.z >> 2;
    const int g  = blockIdx.z & 3;
    const int tx = t & 31, ty = t >> 5;          // thread owns 4x4 outputs at (ty*4+ol, tx*4+cc)

    // ---- channel-invariant staging coordinates (computed once) ----
    int gy_[6], gx_[6];
    #pragma unroll
    for (int k = 0; k < 6; ++k) {
        int u = t + k * 256;
        if (u < 38 * 35) {
            gy_[k] = Y0 - 3 + u / 35;
            gx_[k] = X0 - 4 + (u % 35) * 4;
        } else { gy_[k] = -1; gx_[k] = 0; }
    }

    float4 rv[6];
    auto prefetch = [&](int c) {
        const float* img = color + ((size_t)b * NC + c) * HW;
        #pragma unroll
        for (int k = 0; k < 6; ++k) {
            int gy = gy_[k], gx0 = gx_[k];
            float4 v = make_float4(0.f, 0.f, 0.f, 0.f);
            if (gy >= 0 && gy < H) {
                if (gx0 >= 0 && gx0 <= W - 4) {
                    v = *(const float4*)(img + (size_t)gy * W + gx0);
                } else {
                    float e0 = (gx0 + 0 >= 0 && gx0 + 0 < W) ? img[(size_t)gy * W + gx0 + 0] : 0.f;
                    float e1 = (gx0 + 1 >= 0 && gx0 + 1 < W) ? img[(size_t)gy * W + gx0 + 1] : 0.f;
                    float e2 = (gx0 + 2 >= 0 && gx0 + 2 < W) ? img[(size_t)gy * W + gx0 + 2] : 0.f;
                    float e3 = (gx0 + 3 >= 0 && gx0 + 3 < W) ? img[(size_t)gy * W + gx0 + 3] : 0.f;
                    v = make_float4(e0, e1, e2, e3);
                }
            }
            rv[k] = v;
        }
    };
    auto stage_write = [&]() {
        #pragma unroll
        for (int k = 0; k < 6; ++k) {
            int u = t + k * 256;
            if (u < 38 * 35)
                *(float4*)&A[u / 35][(u % 35) * 4] = rv[k];
        }
    };

    float wmx[4][4], scacc[4][4];
    #pragma unroll
    for (int ol = 0; ol < 4; ++ol)
        #pragma unroll
        for (int cc = 0; cc < 4; ++cc) { wmx[ol][cc] = -INFINITY; scacc[ol][cc] = 0.f; }

    auto phase3 = [&](const float* wc) {                  // P -> acc -> wmx (pure compute)
        float acc[4][4];
        #pragma unroll
        for (int ol = 0; ol < 4; ++ol)
            #pragma unroll
            for (int cc = 0; cc < 4; ++cc) acc[ol][cc] = 0.f;
        #pragma unroll
        for (int pr8 = 0; pr8 < 8; ++pr8) {
            int pr = ty * 4 + pr8;
            float4 q0 = *(const float4*)&P[pr][tx * 4 + 0];
            float4 q1 = *(const float4*)&P[pr][tx * 4 + 4];
            float c8[8] = {q0.x, q0.y, q0.z, q0.w, q1.x, q1.y, q1.z, q1.w};
            #pragma unroll
            for (int ol = 0; ol < 4; ++ol) {
                const int ky = pr8 - ol;
                if (ky >= 0 && ky <= 4) {
                    #pragma unroll
                    for (int cc = 0; cc < 4; ++cc) {
                        float a = acc[ol][cc];
                        #pragma unroll
                        for (int kx = 0; kx < 5; ++kx)
                            a = fmaf(c8[cc + kx], wc[ky * 5 + kx], a);
                        acc[ol][cc] = a;
                    }
                }
            }
        }
        #pragma unroll
        for (int ol = 0; ol < 4; ++ol)
            #pragma unroll
            for (int cc = 0; cc < 4; ++cc)
                wmx[ol][cc] = fmaxf(wmx[ol][cc], acc[ol][cc]);
    };

    prefetch(8 * g);                                       // channel 0 of this group in flight
    const float* wc_prev = nullptr;

    for (int ci = 0; ci < 4; ++ci) {
        const int ce = 8 * g + 2 * ci;
        const int co = ce + 1;
        const float* wc  = wbbx + ce * 25;                 // uniform -> SGPR
        const float wse  = wscore[ce];
        const float wso  = wscore[co];
        const float* imgO = color + ((size_t)b * NC + co) * HW;

        stage_write();                                     // rv -> A (waits on its vmcnt)
        if (ci < 3) prefetch(ce + 2);                      // next even channel in flight

        // odd-channel sc: direct center loads (independent, overlap everything)
        float4 ov[4];
        #pragma unroll
        for (int ol = 0; ol < 4; ++ol)
            ov[ol] = *(const float4*)(imgO + (size_t)(Y0 + ty * 4 + ol) * W + X0 + tx * 4);

        if (wc_prev) phase3(wc_prev);                      // overlap with staging writes

        #pragma unroll
        for (int ol = 0; ol < 4; ++ol) {
            scacc[ol][0] = fmaf(ov[ol].x, wso, scacc[ol][0]);
            scacc[ol][1] = fmaf(ov[ol].y, wso, scacc[ol][1]);
            scacc[ol][2] = fmaf(ov[ol].z, wso, scacc[ol][2]);
            scacc[ol][3] = fmaf(ov[ol].w, wso, scacc[ol][3]);
        }

        __syncthreads();   // A ready; P free (phase3 done block-wide)

        // even-channel sc from staged tile center
        #pragma unroll
        for (int ol = 0; ol < 4; ++ol) {
            float4 v = *(const float4*)&A[3 + ty * 4 + ol][4 + tx * 4];
            scacc[ol][0] = fmaf(v.x, wse, scacc[ol][0]);
            scacc[ol][1] = fmaf(v.y, wse, scacc[ol][1]);
            scacc[ol][2] = fmaf(v.z, wse, scacc[ol][2]);
            scacc[ol][3] = fmaf(v.w, wse, scacc[ol][3]);
        }

        // phase 2: P = box3x3(A)/9, conv zero-padding folded
        for (int u = t; u < 36 * 17; u += 256) {
            int pr = u / 17, ch = u % 17;
            int j0 = ch * 8;
            int gyP = Y0 - 2 + pr;
            float p[8];
            if (gyP >= 0 && gyP < H) {
                float vs[12];
                #pragma unroll
                for (int q = 0; q < 3; ++q) {
                    float4 x0 = *(const float4*)&A[pr + 0][j0 + q * 4];
                    float4 x1 = *(const float4*)&A[pr + 1][j0 + q * 4];
                    float4 x2 = *(const float4*)&A[pr + 2][j0 + q * 4];
                    vs[q * 4 + 0] = x0.x + x1.x + x2.x;
                    vs[q * 4 + 1] = x0.y + x1.y + x2.y;
                    vs[q * 4 + 2] = x0.z + x1.z + x2.z;
                    vs[q * 4 + 3] = x0.w + x1.w + x2.w;
                }
                #pragma unroll
                for (int jj = 0; jj < 8; ++jj) {
                    int gxP = X0 - 2 + j0 + jj;
                    float s = (vs[jj + 1] + vs[jj + 2] + vs[jj + 3]) * (1.f / 9.f);
                    p[jj] = (gxP >= 0 && gxP < W) ? s : 0.f;
                }
            } else {
                #pragma unroll
                for (int jj = 0; jj < 8; ++jj) p[jj] = 0.f;
            }
            *(float4*)&P[pr][j0 + 0] = make_float4(p[0], p[1], p[2], p[3]);
            *(float4*)&P[pr][j0 + 4] = make_float4(p[4], p[5], p[6], p[7]);
        }
        __syncthreads();   // P ready; A readers done -> next stage_write safe

        wc_prev = wc;
    }
    phase3(wc_prev);       // epilogue: last channel

    size_t off = ((size_t)g * NB + b) * HW + (size_t)(Y0 + ty * 4) * W + X0 + tx * 4;
    #pragma unroll
    for (int ol = 0; ol < 4; ++ol) {
        *(float4*)(pw  + off + (size_t)ol * W) = make_float4(wmx[ol][0], wmx[ol][1], wmx[ol][2], wmx[ol][3]);
        *(float4*)(scE + off + (size_t)ol * W) = make_float4(scacc[ol][0], scacc[ol][1], scacc[ol][2], scacc[ol][3]);
    }
}

// ---- fused: sum 4 sc partials -> avgpool5 -> avgpool3 -> sigmoid + per-stripe top10 ----
__global__ __launch_bounds__(256) void k_poolcand(const float* __restrict__ scE,
                                                  float* __restrict__ score_map,
                                                  float* __restrict__ cand) {
    const int sb = blockIdx.x;           // 0..63  (stripe)
    const int b  = blockIdx.y;
    const int t  = threadIdx.x;
    const int y0 = sb * 8;

    __shared__ float A[14][512];
    __shared__ float Bf[14][512];

    for (int r = 0; r < 14; ++r) {
        int gy = y0 - 3 + r;
        for (int xx = t; xx < 512; xx += 256) {
            float v = 0.f;
            if (gy >= 0 && gy < H) {
                size_t idx = (size_t)b * HW + (size_t)gy * W + xx;
                v = scE[idx] + scE[(size_t)NB * HW + idx]
                  + scE[(size_t)2 * NB * HW + idx] + scE[(size_t)3 * NB * HW + idx];
            }
            A[r][xx] = v;
        }
    }
    __syncthreads();
    for (int r = 0; r < 14; ++r)
        for (int xx = t; xx < 512; xx += 256) {
            float s = 0.f;
            #pragma unroll
            for (int d = -2; d <= 2; ++d) {
                int x2 = xx + d;
                if (x2 >= 0 && x2 < 512) s += A[r][x2];
            }
            Bf[r][xx] = s;
        }
    __syncthreads();
    for (int r2 = 0; r2 < 10; ++r2) {
        int gy = y0 - 1 + r2;
        for (int xx = t; xx < 512; xx += 256) {
            float s = 0.f;
            if (gy >= 0 && gy < H) {
                #pragma unroll
                for (int d = 0; d < 5; ++d) s += Bf[r2 + d][xx];
                s *= (1.f / 25.f);
            }
            A[r2][xx] = s;
        }
    }
    __syncthreads();
    for (int r2 = 0; r2 < 10; ++r2)
        for (int xx = t; xx < 512; xx += 256) {
            float s = 0.f;
            #pragma unroll
            for (int d = -1; d <= 1; ++d) {
                int x2 = xx + d;
                if (x2 >= 0 && x2 < 512) s += A[r2][x2];
            }
            Bf[r2][xx] = s;
        }
    __syncthreads();

    float top[10];
    #pragma unroll
    for (int k = 0; k < 10; ++k) top[k] = -INFINITY;

    for (int r3 = 0; r3 < 8; ++r3) {
        for (int xx = t; xx < 512; xx += 256) {
            float sv = (Bf[r3][xx] + Bf[r3 + 1][xx] + Bf[r3 + 2][xx]) * (1.f / 9.f);
            score_map[(size_t)b * HW + (size_t)(y0 + r3) * W + xx] = sv;
            float s = 1.f / (1.f + expf(-sv));
            if (s > top[9]) {
                top[9] = s;
                #pragma unroll
                for (int k = 9; k > 0; --k)
                    if (top[k] > top[k - 1]) { float tmp = top[k - 1]; top[k - 1] = top[k]; top[k] = tmp; }
            }
        }
    }

    __shared__ float sv_[256];
    __shared__ int   si_[256];
    __shared__ int   swin;
    int ptr = 0;
    for (int r = 0; r < 10; ++r) {
        sv_[t] = (ptr < 10) ? top[ptr] : -INFINITY;
        si_[t] = t;
        __syncthreads();
        for (int off = 128; off > 0; off >>= 1) {
            if (t < off && sv_[t + off] > sv_[t]) { sv_[t] = sv_[t + off]; si_[t] = si_[t + off]; }
            __syncthreads();
        }
        if (t == 0) { cand[((size_t)b * 64 + sb) * 10 + r] = sv_[0]; swin = si_[0]; }
        __syncthreads();
        if (t == swin) ptr++;
        __syncthreads();
    }
}

// ---- 10th-largest over 640 candidates (tie-robust rank count) ----
__global__ __launch_bounds__(256) void k_v10(const float* __restrict__ cand, float* __restrict__ v10) {
    int b = blockIdx.x, t = threadIdx.x;
    __shared__ float c[640];
    for (int j = t; j < 640; j += 256) c[j] = cand[b * 640 + j];
    __syncthreads();
    for (int j = t; j < 640; j += 256) {
        float v = c[j];
        int gt = 0, eq = 0;
        for (int k = 0; k < 640; ++k) { gt += (c[k] > v); eq += (c[k] == v); }
        if (gt <= 9 && gt + eq >= 10) v10[b] = v;
    }
}

// ---- final decode (max over 4 partial pw buffers; smap = POOLED score map) ----
__global__ __launch_bounds__(256) void k_final(const float* __restrict__ smap,
                                               const float* __restrict__ pw,
                                               const float* __restrict__ v10,
                                               float* __restrict__ outbuf,
                                               float* __restrict__ mbuf) {
    int p = blockIdx.x * 256 + threadIdx.x;
    if (p >= NB * HW) return;
    int b = p / HW, i = p % HW;
    float scv = smap[p];
    float s   = 1.f / (1.f + expf(-scv));          // same formula as k_poolcand -> identical bits
    float s10 = v10[b];
    bool  m   = (s >= s10 && s > 0.6f) || (s > 0.9f);
    size_t idx = (size_t)b * HW + i;
    float wmv = fmaxf(fmaxf(pw[idx], pw[(size_t)NB * HW + idx]),
                      fmaxf(pw[(size_t)2 * NB * HW + idx], pw[(size_t)3 * NB * HW + idx]));
    // reference quirk: w = channel0 (score_map), h = channel1 (wmax)
    float wv = expf(scv) * 10.f;
    float hv = expf(wmv) * 10.f;
    float xs = (float)(i & (W - 1));
    float ys = (float)(i >> 9);
    float o0 = 0.f, o1 = 0.f, o2 = 0.f, o3 = 0.f, o4 = 0.f;
    if (m) {
        o0 = s;
        o1 = floorf(xs - wv);
        o2 = floorf(ys - hv);
        o3 = ceilf(xs + wv);
        o4 = ceilf(ys + hv);
    }
    size_t ob = (size_t)p * 5;
    outbuf[ob + 0] = o0; outbuf[ob + 1] = o1; outbuf[ob + 2] = o2;
    outbuf[ob + 3] = o3; outbuf[ob + 4] = o4;
    mbuf[p] = m ? 1.f : 0.f;
}

extern "C" void kernel_launch(void* const* d_in, const int* in_sizes, int n_in,
                              void* d_out, int out_size, void* d_ws, size_t ws_size,
                              hipStream_t stream) {
    // inputs: mask (unused), color, w_bbx, w_score
    const float* color  = (const float*)d_in[1];
    const float* wbbx   = (const float*)d_in[2];
    const float* wscore = (const float*)d_in[3];

    float* out       = (float*)d_out;
    float* score_map = out;                          // 1048576
    float* outbuf    = out + 1048576;                // 5242880
    float* mbuf      = out + 1048576 + 5242880;      // 1048576

    float* ws   = (float*)d_ws;
    float* pw   = ws;                                // 4 planes x NB*HW = 16 MB
    float* scE  = ws + (size_t)4 * NB * HW;          // 4 planes x NB*HW = 16 MB
    float* cand = ws + (size_t)8 * NB * HW;          // 4*640
    float* v10  = cand + 2560;                       // 4

    k_whmax_sc <<<dim3(4, 16, NB * 4), 256, 0, stream>>>(color, wbbx, wscore, pw, scE);
    k_poolcand <<<dim3(64, NB), 256, 0, stream>>>(scE, score_map, cand);
    k_v10      <<<4, 256, 0, stream>>>(cand, v10);
    k_final    <<<(NB * HW + 255) / 256, 256, 0, stream>>>(score_map, pw, v10, outbuf, mbuf);
}

// Round 16
// 121.086 us; speedup vs baseline: 1.1442x; 1.1442x over previous
//
#include <hip/hip_runtime.h>
#include <math.h>

#define H 512
#define W 512
#define HW (H*W)
#define NB 4
#define NC 32

// ---- fused: [8 channels/group] score-conv partial + avgpool3x3 -> conv5x5 -> even max ----
// R14 structure (no T14 pipeline — R15 showed it regresses). Phase 2 re-chunked to
// 16B/lane so all LDS reads are near-linear (R15 profile: 9.8M conflict cycles from
// the 32B-stride 17-chunk decomposition).
__global__ __launch_bounds__(256) void k_whmax_sc(const float* __restrict__ color,
                                                  const float* __restrict__ wbbx,
                                                  const float* __restrict__ wscore,
                                                  float* __restrict__ pw,
                                                  float* __restrict__ scE) {
    __shared__ float A[38][140];   // rows Y0-3..Y0+34, cols X0-4..X0+135 (35 float4/row: linear)
    __shared__ float P[36][136];   // rows Y0-2..Y0+33, cols X0-2..X0+133 (34 float4/row: linear)

    const int t  = threadIdx.x;
    const int X0 = blockIdx.x * 128;
    const int Y0 = blockIdx.y * 32;
    const int b  = blockIdx.z >> 2;
    const int g  = blockIdx.z & 3;
    const int tx = t & 31, ty = t >> 5;          // thread owns 4x4 outputs at (ty*4+ol, tx*4+cc)

    float wmx[4][4], scacc[4][4];
    #pragma unroll
    for (int ol = 0; ol < 4; ++ol)
        #pragma unroll
        for (int cc = 0; cc < 4; ++cc) { wmx[ol][cc] = -INFINITY; scacc[ol][cc] = 0.f; }

    for (int ci = 0; ci < 4; ++ci) {
        const int ce = 8 * g + 2 * ci;                       // even channel
        const int co = ce + 1;                               // odd channel
        const float* img  = color + ((size_t)b * NC + ce) * HW;
        const float* imgO = color + ((size_t)b * NC + co) * HW;
        const float* wc   = wbbx + ce * 25;                  // uniform -> SGPR
        const float wse   = wscore[ce];
        const float wso   = wscore[co];

        // ---- stage A (zero-padded halo of even channel); LDS addr = u*16 B -> linear ----
        for (int u = t; u < 38 * 35; u += 256) {
            int r = u / 35, c4 = u % 35;
            int gy = Y0 - 3 + r, gx0 = X0 - 4 + c4 * 4;
            float4 v = make_float4(0.f, 0.f, 0.f, 0.f);
            if (gy >= 0 && gy < H) {
                if (gx0 >= 0 && gx0 <= W - 4) {
                    v = *(const float4*)(img + (size_t)gy * W + gx0);
                } else {
                    float e0 = (gx0 + 0 >= 0 && gx0 + 0 < W) ? img[(size_t)gy * W + gx0 + 0] : 0.f;
                    float e1 = (gx0 + 1 >= 0 && gx0 + 1 < W) ? img[(size_t)gy * W + gx0 + 1] : 0.f;
                    float e2 = (gx0 + 2 >= 0 && gx0 + 2 < W) ? img[(size_t)gy * W + gx0 + 2] : 0.f;
                    float e3 = (gx0 + 3 >= 0 && gx0 + 3 < W) ? img[(size_t)gy * W + gx0 + 3] : 0.f;
                    v = make_float4(e0, e1, e2, e3);
                }
            }
            *(float4*)&A[r][c4 * 4] = v;
        }

        // ---- odd channel sc: direct center reads (independent; overlaps staging) ----
        float4 ov[4];
        #pragma unroll
        for (int ol = 0; ol < 4; ++ol)
            ov[ol] = *(const float4*)(imgO + (size_t)(Y0 + ty * 4 + ol) * W + X0 + tx * 4);
        #pragma unroll
        for (int ol = 0; ol < 4; ++ol) {
            scacc[ol][0] = fmaf(ov[ol].x, wso, scacc[ol][0]);
            scacc[ol][1] = fmaf(ov[ol].y, wso, scacc[ol][1]);
            scacc[ol][2] = fmaf(ov[ol].z, wso, scacc[ol][2]);
            scacc[ol][3] = fmaf(ov[ol].w, wso, scacc[ol][3]);
        }

        __syncthreads();   // A ready; also guarantees prev iteration's phase3 (P readers) done

        // ---- even channel sc from staged tile center ----
        #pragma unroll
        for (int ol = 0; ol < 4; ++ol) {
            float4 v = *(const float4*)&A[3 + ty * 4 + ol][4 + tx * 4];
            scacc[ol][0] = fmaf(v.x, wse, scacc[ol][0]);
            scacc[ol][1] = fmaf(v.y, wse, scacc[ol][1]);
            scacc[ol][2] = fmaf(v.z, wse, scacc[ol][2]);
            scacc[ol][3] = fmaf(v.w, wse, scacc[ol][3]);
        }

        // ---- phase 2: P = box3x3(A)/9, conv zero-pad folded; 4 cols/lane (16B chunks) ----
        for (int u = t; u < 36 * 34; u += 256) {
            int pr = u / 34, ch = u % 34;
            int j0 = ch * 4;                                  // P cols j0..j0+3 (<=135)
            int gyP = Y0 - 2 + pr;
            float4 pv = make_float4(0.f, 0.f, 0.f, 0.f);
            if (gyP >= 0 && gyP < H) {
                // need A cols j0+1..j0+6 -> read j0..j0+7 (two near-linear b128 per row)
                float vs[8];
                float4 a0 = *(const float4*)&A[pr + 0][j0 + 0];
                float4 b0 = *(const float4*)&A[pr + 0][j0 + 4];
                float4 a1 = *(const float4*)&A[pr + 1][j0 + 0];
                float4 b1 = *(const float4*)&A[pr + 1][j0 + 4];
                float4 a2 = *(const float4*)&A[pr + 2][j0 + 0];
                float4 b2 = *(const float4*)&A[pr + 2][j0 + 4];
                vs[0] = a0.x + a1.x + a2.x;
                vs[1] = a0.y + a1.y + a2.y;
                vs[2] = a0.z + a1.z + a2.z;
                vs[3] = a0.w + a1.w + a2.w;
                vs[4] = b0.x + b1.x + b2.x;
                vs[5] = b0.y + b1.y + b2.y;
                vs[6] = b0.z + b1.z + b2.z;
                vs[7] = b0.w + b1.w + b2.w;
                float p[4];
                #pragma unroll
                for (int jj = 0; jj < 4; ++jj) {
                    int gxP = X0 - 2 + j0 + jj;
                    float s = (vs[jj + 1] + vs[jj + 2] + vs[jj + 3]) * (1.f / 9.f);
                    p[jj] = (gxP >= 0 && gxP < W) ? s : 0.f;
                }
                pv = make_float4(p[0], p[1], p[2], p[3]);
            }
            *(float4*)&P[pr][j0] = pv;                        // u*16 B -> linear store
        }
        __syncthreads();

        // ---- phase 3: conv5x5 from P (SGPR weights), fmax into wmx ----
        float acc[4][4];
        #pragma unroll
        for (int ol = 0; ol < 4; ++ol)
            #pragma unroll
            for (int cc = 0; cc < 4; ++cc) acc[ol][cc] = 0.f;

        #pragma unroll
        for (int pr8 = 0; pr8 < 8; ++pr8) {
            int pr = ty * 4 + pr8;
            float4 q0 = *(const float4*)&P[pr][tx * 4 + 0];
            float4 q1 = *(const float4*)&P[pr][tx * 4 + 4];
            float c8[8] = {q0.x, q0.y, q0.z, q0.w, q1.x, q1.y, q1.z, q1.w};
            #pragma unroll
            for (int ol = 0; ol < 4; ++ol) {
                const int ky = pr8 - ol;
                if (ky >= 0 && ky <= 4) {
                    #pragma unroll
                    for (int cc = 0; cc < 4; ++cc) {
                        float a = acc[ol][cc];
                        #pragma unroll
                        for (int kx = 0; kx < 5; ++kx)
                            a = fmaf(c8[cc + kx], wc[ky * 5 + kx], a);
                        acc[ol][cc] = a;
                    }
                }
            }
        }
        #pragma unroll
        for (int ol = 0; ol < 4; ++ol)
            #pragma unroll
            for (int cc = 0; cc < 4; ++cc)
                wmx[ol][cc] = fmaxf(wmx[ol][cc], acc[ol][cc]);
    }

    size_t off = ((size_t)g * NB + b) * HW + (size_t)(Y0 + ty * 4) * W + X0 + tx * 4;
    #pragma unroll
    for (int ol = 0; ol < 4; ++ol) {
        *(float4*)(pw  + off + (size_t)ol * W) = make_float4(wmx[ol][0], wmx[ol][1], wmx[ol][2], wmx[ol][3]);
        *(float4*)(scE + off + (size_t)ol * W) = make_float4(scacc[ol][0], scacc[ol][1], scacc[ol][2], scacc[ol][3]);
    }
}

// ---- fused: sum 4 sc partials -> avgpool5 -> avgpool3 -> sigmoid + per-stripe top10 ----
__global__ __launch_bounds__(256) void k_poolcand(const float* __restrict__ scE,
                                                  float* __restrict__ score_map,
                                                  float* __restrict__ cand) {
    const int sb = blockIdx.x;           // 0..63  (stripe)
    const int b  = blockIdx.y;
    const int t  = threadIdx.x;
    const int y0 = sb * 8;

    __shared__ float A[14][512];
    __shared__ float Bf[14][512];

    for (int r = 0; r < 14; ++r) {
        int gy = y0 - 3 + r;
        for (int xx = t; xx < 512; xx += 256) {
            float v = 0.f;
            if (gy >= 0 && gy < H) {
                size_t idx = (size_t)b * HW + (size_t)gy * W + xx;
                v = scE[idx] + scE[(size_t)NB * HW + idx]
                  + scE[(size_t)2 * NB * HW + idx] + scE[(size_t)3 * NB * HW + idx];
            }
            A[r][xx] = v;
        }
    }
    __syncthreads();
    for (int r = 0; r < 14; ++r)
        for (int xx = t; xx < 512; xx += 256) {
            float s = 0.f;
            #pragma unroll
            for (int d = -2; d <= 2; ++d) {
                int x2 = xx + d;
                if (x2 >= 0 && x2 < 512) s += A[r][x2];
            }
            Bf[r][xx] = s;
        }
    __syncthreads();
    for (int r2 = 0; r2 < 10; ++r2) {
        int gy = y0 - 1 + r2;
        for (int xx = t; xx < 512; xx += 256) {
            float s = 0.f;
            if (gy >= 0 && gy < H) {
                #pragma unroll
                for (int d = 0; d < 5; ++d) s += Bf[r2 + d][xx];
                s *= (1.f / 25.f);
            }
            A[r2][xx] = s;
        }
    }
    __syncthreads();
    for (int r2 = 0; r2 < 10; ++r2)
        for (int xx = t; xx < 512; xx += 256) {
            float s = 0.f;
            #pragma unroll
            for (int d = -1; d <= 1; ++d) {
                int x2 = xx + d;
                if (x2 >= 0 && x2 < 512) s += A[r2][x2];
            }
            Bf[r2][xx] = s;
        }
    __syncthreads();

    float top[10];
    #pragma unroll
    for (int k = 0; k < 10; ++k) top[k] = -INFINITY;

    for (int r3 = 0; r3 < 8; ++r3) {
        for (int xx = t; xx < 512; xx += 256) {
            float sv = (Bf[r3][xx] + Bf[r3 + 1][xx] + Bf[r3 + 2][xx]) * (1.f / 9.f);
            score_map[(size_t)b * HW + (size_t)(y0 + r3) * W + xx] = sv;
            float s = 1.f / (1.f + expf(-sv));
            if (s > top[9]) {
                top[9] = s;
                #pragma unroll
                for (int k = 9; k > 0; --k)
                    if (top[k] > top[k - 1]) { float tmp = top[k - 1]; top[k - 1] = top[k]; top[k] = tmp; }
            }
        }
    }

    __shared__ float sv_[256];
    __shared__ int   si_[256];
    __shared__ int   swin;
    int ptr = 0;
    for (int r = 0; r < 10; ++r) {
        sv_[t] = (ptr < 10) ? top[ptr] : -INFINITY;
        si_[t] = t;
        __syncthreads();
        for (int off = 128; off > 0; off >>= 1) {
            if (t < off && sv_[t + off] > sv_[t]) { sv_[t] = sv_[t + off]; si_[t] = si_[t + off]; }
            __syncthreads();
        }
        if (t == 0) { cand[((size_t)b * 64 + sb) * 10 + r] = sv_[0]; swin = si_[0]; }
        __syncthreads();
        if (t == swin) ptr++;
        __syncthreads();
    }
}

// ---- 10th-largest over 640 candidates (tie-robust rank count) ----
__global__ __launch_bounds__(256) void k_v10(const float* __restrict__ cand, float* __restrict__ v10) {
    int b = blockIdx.x, t = threadIdx.x;
    __shared__ float c[640];
    for (int j = t; j < 640; j += 256) c[j] = cand[b * 640 + j];
    __syncthreads();
    for (int j = t; j < 640; j += 256) {
        float v = c[j];
        int gt = 0, eq = 0;
        for (int k = 0; k < 640; ++k) { gt += (c[k] > v); eq += (c[k] == v); }
        if (gt <= 9 && gt + eq >= 10) v10[b] = v;
    }
}

// ---- final decode (max over 4 partial pw buffers; smap = POOLED score map) ----
__global__ __launch_bounds__(256) void k_final(const float* __restrict__ smap,
                                               const float* __restrict__ pw,
                                               const float* __restrict__ v10,
                                               float* __restrict__ outbuf,
                                               float* __restrict__ mbuf) {
    int p = blockIdx.x * 256 + threadIdx.x;
    if (p >= NB * HW) return;
    int b = p / HW, i = p % HW;
    float scv = smap[p];
    float s   = 1.f / (1.f + expf(-scv));          // same formula as k_poolcand -> identical bits
    float s10 = v10[b];
    bool  m   = (s >= s10 && s > 0.6f) || (s > 0.9f);
    size_t idx = (size_t)b * HW + i;
    float wmv = fmaxf(fmaxf(pw[idx], pw[(size_t)NB * HW + idx]),
                      fmaxf(pw[(size_t)2 * NB * HW + idx], pw[(size_t)3 * NB * HW + idx]));
    // reference quirk: w = channel0 (score_map), h = channel1 (wmax)
    float wv = expf(scv) * 10.f;
    float hv = expf(wmv) * 10.f;
    float xs = (float)(i & (W - 1));
    float ys = (float)(i >> 9);
    float o0 = 0.f, o1 = 0.f, o2 = 0.f, o3 = 0.f, o4 = 0.f;
    if (m) {
        o0 = s;
        o1 = floorf(xs - wv);
        o2 = floorf(ys - hv);
        o3 = ceilf(xs + wv);
        o4 = ceilf(ys + hv);
    }
    size_t ob = (size_t)p * 5;
    outbuf[ob + 0] = o0; outbuf[ob + 1] = o1; outbuf[ob + 2] = o2;
    outbuf[ob + 3] = o3; outbuf[ob + 4] = o4;
    mbuf[p] = m ? 1.f : 0.f;
}

extern "C" void kernel_launch(void* const* d_in, const int* in_sizes, int n_in,
                              void* d_out, int out_size, void* d_ws, size_t ws_size,
                              hipStream_t stream) {
    // inputs: mask (unused), color, w_bbx, w_score
    const float* color  = (const float*)d_in[1];
    const float* wbbx   = (const float*)d_in[2];
    const float* wscore = (const float*)d_in[3];

    float* out       = (float*)d_out;
    float* score_map = out;                          // 1048576
    float* outbuf    = out + 1048576;                // 5242880
    float* mbuf      = out + 1048576 + 5242880;      // 1048576

    float* ws   = (float*)d_ws;
    float* pw   = ws;                                // 4 planes x NB*HW = 16 MB
    float* scE  = ws + (size_t)4 * NB * HW;          // 4 planes x NB*HW = 16 MB
    float* cand = ws + (size_t)8 * NB * HW;          // 4*640
    float* v10  = cand + 2560;                       // 4

    k_whmax_sc <<<dim3(4, 16, NB * 4), 256, 0, stream>>>(color, wbbx, wscore, pw, scE);
    k_poolcand <<<dim3(64, NB), 256, 0, stream>>>(scE, score_map, cand);
    k_v10      <<<4, 256, 0, stream>>>(cand, v10);
    k_final    <<<(NB * HW + 255) / 256, 256, 0, stream>>>(score_map, pw, v10, outbuf, mbuf);
}